// Round 17
// baseline (118.544 us; speedup 1.0000x reference)
//
#include <hip/hip_runtime.h>
#include <hip/hip_bf16.h>

#define Dx 300

// float-offsets into ws.
// Cross-kernel edges (ED, HEADF) use NORMAL stores — the K_A/K_B boundary
// provides flush/invalidate. Intra-kernel cross-block edges (REPB in K_A;
// ATB/ATTNF in K_B) use sc0/sc1 write-through + flag protocol (r12-proven).
#define ED     0             // float2 [1024][300] {exd, rep}
#define HEADF  614400        // f32 [1024][300]
#define ATTNF  921600        // f32 [1024][300]
#define U_BASE 1228800       // ushort region (float offset)
#define REPB   0             // bf16 [1024][320]
#define ATB    327680        // bf16 [1024][320]
#define SYNC_FOFF 2000000    // flag state (memset before launch)

#define AG __HIP_MEMORY_SCOPE_AGENT

typedef __attribute__((ext_vector_type(8))) short short8;
typedef __attribute__((ext_vector_type(4))) float f32x4;

union S8 { unsigned int u[4]; unsigned short s[8]; short8 v; };

__device__ __forceinline__ float bf2f(unsigned short u) {
    union { unsigned int i; float f; } v; v.i = ((unsigned int)u) << 16; return v.f;
}
__device__ __forceinline__ unsigned short f2bf(float x) {   // round-half-up
    union { float f; unsigned int i; } u; u.f = x;
    return (unsigned short)((u.i + 0x8000u) >> 16);
}
__device__ __forceinline__ float ldf(const void* p, int idx, int isbf) {
    return isbf ? bf2f(((const unsigned short*)p)[idx]) : ((const float*)p)[idx];
}

// write-through stores (visible at coherence point once vmcnt acks)
__device__ __forceinline__ void st_wt_f32(float* p, float v) {
    asm volatile("global_store_dword %0, %1, off sc0 sc1"
                 :: "v"(p), "v"(v) : "memory");
}
__device__ __forceinline__ void st_wt_u16(unsigned short* p, unsigned short v) {
    unsigned int vv = v;
    asm volatile("global_store_short %0, %1, off sc0 sc1"
                 :: "v"(p), "v"(vv) : "memory");
}

__device__ __forceinline__ void load8f(const float* rowp, int kb, int kmax,
                                       int valid, float* x) {
    if (valid && kb + 8 <= kmax) {
        float4 a = *(const float4*)(rowp + kb);
        float4 b = *(const float4*)(rowp + kb + 4);
        x[0]=a.x; x[1]=a.y; x[2]=a.z; x[3]=a.w;
        x[4]=b.x; x[5]=b.y; x[6]=b.z; x[7]=b.w;
    } else {
        #pragma unroll
        for (int j = 0; j < 8; ++j) {
            int k = kb + j;
            x[j] = (valid && k < kmax) ? rowp[k] : 0.f;
        }
    }
}
__device__ __forceinline__ short8 pack8(const float* x) {
    S8 H;
    #pragma unroll
    for (int p = 0; p < 4; ++p) {
        union { float f; unsigned int i; } a, b;
        a.f = x[2*p]; b.f = x[2*p+1];
        H.u[p] = ((a.i + 0x8000u) >> 16) | ((b.i + 0x8000u) & 0xFFFF0000u);
    }
    return H.v;
}
__device__ __forceinline__ short8 load8bf(const unsigned short* rowp, int kb,
                                          int kmax, int valid) {
    S8 R;
    if (valid && kb + 8 <= kmax) {
        ushort4 a = *(const ushort4*)(rowp + kb);
        ushort4 b = *(const ushort4*)(rowp + kb + 4);
        R.s[0]=a.x; R.s[1]=a.y; R.s[2]=a.z; R.s[3]=a.w;
        R.s[4]=b.x; R.s[5]=b.y; R.s[6]=b.z; R.s[7]=b.w;
    } else {
        #pragma unroll
        for (int j = 0; j < 8; ++j) {
            int k = kb + j;
            R.s[j] = (valid && k < kmax) ? rowp[k] : (unsigned short)0;
        }
    }
    return R.v;
}
__device__ __forceinline__ short8 loadB(const void* W, int row, int kb, int isbf,
                                        int valid) {
    if (isbf) return load8bf((const unsigned short*)W + row * 300, kb, 300, valid);
    float t[8];
    load8f((const float*)W + row * 300, kb, 300, valid, t);
    return pack8(t);
}

__device__ __forceinline__ int detect_isbf(const void* Wfc, int tid, int* s_isbf) {
    if (tid < 64) {
        float v = bf2f(((const unsigned short*)Wfc)[tid]);
        int ok = fabsf(v) < 1.0f;
        unsigned long long bal = __ballot(ok);
        if (tid == 0) *s_isbf = (bal == ~0ull) ? 1 : 0;
    }
    __syncthreads();
    return *s_isbf;
}

// relaxed spin until *p >= target; bounded (lost block => visible fail)
__device__ __forceinline__ void spin_ge(int* p, int target) {
    int t = 0;
    while (__hip_atomic_load(p, __ATOMIC_RELAXED, AG) < target) {
        __builtin_amdgcn_s_sleep(1);
        if (++t > 400000) break;
    }
    asm volatile("" ::: "memory");
}

// SYNC slots (int index, 256 B apart):
//   cnt1[mt]  = mt*64           mm1 tiles (target 5), mt 0..63   [K_A]
//   cnt3[gt]  = (100+gt)*64     attn rows done per 16-row tile   [K_B]

// ---------------------------------------------------------------------------
// K_A: mm1 -> cnt1 flags -> mm2.  grid 640 x 256.
// XCD-pair batch swizzle: bat=(blk&7)>>1, li=((blk>>3)<<1)|(blk&1) in 0..159.
// REPB (mm1->mm2 intra-kernel edge) via sc1; ED/HEADF normal (next kernel).
// ---------------------------------------------------------------------------
__global__ __launch_bounds__(256) void k_a(
        const void* __restrict__ Xv, const void* __restrict__ Wfc,
        const void* __restrict__ bfc, const void* __restrict__ W1,
        const void* __restrict__ W2,  const void* __restrict__ b1v,
        float* __restrict__ ws) {
    __shared__ int s_isbf;
    const int tid = threadIdx.x, blk = blockIdx.x;
    const int isbf = detect_isbf(Wfc, tid, &s_isbf);
    unsigned short* U = (unsigned short*)(ws + U_BASE);
    int* S = (int*)(ws + SYNC_FOFF);
    const int bat = (blk & 7) >> 1;
    const int li  = ((blk >> 3) << 1) | (blk & 1);   // 0..159

    // ---- Phase 1: mm1 (li < 80) ----
    if (li < 80) {
        const int mt = bat * 16 + li / 5, nt = li % 5;
        const int w = tid >> 6, l = tid & 63;
        const int m0 = mt * 16, lm = l & 15, koff = (l >> 4) * 8;
        const int nrow = nt * 64 + w * 16 + lm;          // 0..319
        const int bval = nrow < 300;
        const int ncl = bval ? nrow : 0;
        f32x4 acc = {0.f, 0.f, 0.f, 0.f};
        if (isbf) {
            const unsigned short* Xp = (const unsigned short*)Xv + (m0 + lm) * 300;
            #pragma unroll
            for (int ks = 0; ks < 10; ++ks) {
                short8 a = load8bf(Xp, ks*32 + koff, 300, 1);
                short8 b = loadB(Wfc, ncl, ks*32 + koff, 1, bval);
                acc = __builtin_amdgcn_mfma_f32_16x16x32_bf16(a, b, acc, 0, 0, 0);
            }
        } else {
            const float* Xp = (const float*)Xv + (m0 + lm) * 300;
            #pragma unroll
            for (int ks = 0; ks < 10; ++ks) {
                float t[8]; load8f(Xp, ks*32 + koff, 300, 1, t);
                short8 a = pack8(t);
                short8 b = loadB(Wfc, ncl, ks*32 + koff, 0, bval);
                acc = __builtin_amdgcn_mfma_f32_16x16x32_bf16(a, b, acc, 0, 0, 0);
            }
        }
        if (bval) {
            float bb = ldf(bfc, nrow, isbf);
            #pragma unroll
            for (int r = 0; r < 4; ++r) {
                int mg = m0 + (l >> 4) * 4 + r;
                float v = acc[r] + bb;
                v = v > 0.f ? v : (__expf(v) - 1.f);
                ws[ED + (mg * 300 + nrow) * 2 + 1] = v;      // ed.y (K_B, normal)
                st_wt_u16(U + REPB + mg * 320 + nrow, f2bf(v));  // mm2 edge, sc1
            }
        } else {
            #pragma unroll
            for (int r = 0; r < 4; ++r) {
                int mg = m0 + (l >> 4) * 4 + r;
                st_wt_u16(U + REPB + mg * 320 + nrow, 0);
            }
        }
    }
    __syncthreads();                                // drains vmcnt (sc1 acked)
    if (li < 80 && tid == 0)
        __hip_atomic_fetch_add(S + (bat * 16 + li / 5) * 64, 1,
                               __ATOMIC_RELAXED, AG);

    // ---- Phase 2: mm2, one unit per block ----
    {
        const int mt = bat * 16 + li / 10, nt10 = li % 10;
        if (tid == 0) spin_ge(S + mt * 64, 5);
        __syncthreads();
        const int w = tid >> 6, l = tid & 63;
        const int m0 = mt * 16, lm = l & 15, koff = (l >> 4) * 8;
        const int ng = nt10 * 64 + w * 16 + lm;      // 0..639
        const int wsel = ng < 320;
        const int wrow = wsel ? ng : ng - 320;
        const int bval = wrow < 300;
        const int ncl = bval ? wrow : 0;
        const void* Wsel = wsel ? W1 : W2;
        const unsigned short* ap = U + REPB + (m0 + lm) * 320 + koff;
        f32x4 acc = {0.f, 0.f, 0.f, 0.f};
        #pragma unroll
        for (int ks = 0; ks < 10; ++ks) {
            short8 a = *(const short8*)(ap + ks * 32);
            short8 b = loadB(Wsel, ncl, ks*32 + koff, isbf, bval);
            acc = __builtin_amdgcn_mfma_f32_16x16x32_bf16(a, b, acc, 0, 0, 0);
        }
        if (ng < 300) {
            float bb = ldf(b1v, ng, isbf);
            #pragma unroll
            for (int r = 0; r < 4; ++r) {
                int mg = m0 + (l >> 4) * 4 + r;
                ws[ED + (mg * 300 + ng) * 2] = __expf(0.4f * (acc[r] + bb));  // ed.x
            }
        } else if (ng >= 320 && ng < 620) {
            #pragma unroll
            for (int r = 0; r < 4; ++r) {
                int mg = m0 + (l >> 4) * 4 + r;
                ws[HEADF + mg * 300 + (ng - 320)] = acc[r];
            }
        }
    }
}

// ---------------------------------------------------------------------------
// K_B: attn (compacted valid rows) -> cnt3 flags -> mm3.  grid 512 x 320.
// ED/HEADF read NORMALLY (boundary gives coherence). ATB/ATTNF (attn->mm3
// intra-kernel edges) via sc1 + flags.
// ---------------------------------------------------------------------------
__global__ __launch_bounds__(320) void k_b(
        const void* __restrict__ Wfc, const void* __restrict__ Wf1,
        const void* __restrict__ Wf2, const void* __restrict__ bfv,
        const int* __restrict__ mask, float* __restrict__ ws,
        void* __restrict__ outv) {
    __shared__ int s_isbf;
    __shared__ unsigned short vlist[256];
    __shared__ int s_cnt, s_tgt;
    const int tid = threadIdx.x, blk = blockIdx.x;
    const int isbf = detect_isbf(Wfc, tid, &s_isbf);
    unsigned short* U = (unsigned short*)(ws + U_BASE);
    int* S = (int*)(ws + SYNC_FOFF);
    const int bat = (blk & 7) >> 1;
    const int li  = ((blk >> 3) << 1) | (blk & 1);   // 0..127
    const int base = bat * 256;

    // ---- Phase 3: attn, pair (2*li, 2*li+1) of vlist ----
    {
        if (tid < 64) {
            int basec = 0;
            #pragma unroll
            for (int c = 0; c < 4; ++c) {
                const int j = c * 64 + tid;
                const int mv = mask[base + j] != 0;
                unsigned long long bal = __ballot(mv);
                int pos = basec + __popcll(bal & ((1ull << tid) - 1ull));
                if (mv) vlist[pos] = (unsigned short)j;
                basec += __popcll(bal);
            }
            if (tid == 0) s_cnt = basec;
        }
        __syncthreads();
        const int cnt = s_cnt;
        const int iu = 2 * li;
        if (iu < cnt) {
            const int ia = vlist[iu];
            const int hasB = (iu + 1 < cnt);
            const int ib = hasB ? vlist[iu + 1] : ia;
            const int ga = base + ia, gb = base + ib;
            const int d = tid;
            if (d >= 300) {
                st_wt_u16(U + ATB + ga * 320 + d, 0);
                if (hasB) st_wt_u16(U + ATB + gb * 320 + d, 0);
            } else {
                const float pwa = __expf(0.4f * ws[HEADF + ga * 300 + d]);
                const float pwb = __expf(0.4f * ws[HEADF + gb * 300 + d]);
                const float2* ep2 = ((const float2*)(ws + ED)) + base * Dx + d;
                float sa = 0.f, ra = 0.f, sb = 0.f, rb = 0.f;
                if (hasB) {                      // prologue: j=ib hits row A only
                    float2 v = ep2[ib * Dx];
                    float ua = fmaf(v.x, pwa, 1.0f);
                    float ea = __expf(-10.0f * __builtin_amdgcn_rcpf(ua));
                    sa += ea; ra = fmaf(ea, v.y, ra);
                }
                #pragma unroll 8
                for (int t = iu + 2; t < cnt; ++t) {
                    const int j = vlist[t];
                    float2 v = ep2[j * Dx];
                    float ua = fmaf(v.x, pwa, 1.0f);
                    float ub = fmaf(v.x, pwb, 1.0f);
                    float ea = __expf(-10.0f * __builtin_amdgcn_rcpf(ua));
                    float eb = __expf(-10.0f * __builtin_amdgcn_rcpf(ub));
                    sa += ea; ra = fmaf(ea, v.y, ra);
                    sb += eb; rb = fmaf(eb, v.y, rb);
                }
                const float dena = sa + (sa == 0.f ? 1.f : 0.f) + 1e-20f;
                const float aa = ra / dena;
                st_wt_f32(ws + ATTNF + ga * Dx + d, aa);
                st_wt_u16(U + ATB + ga * 320 + d, f2bf(aa));
                if (hasB) {
                    const float denb = sb + (sb == 0.f ? 1.f : 0.f) + 1e-20f;
                    const float ab = rb / denb;
                    st_wt_f32(ws + ATTNF + gb * Dx + d, ab);
                    st_wt_u16(U + ATB + gb * 320 + d, f2bf(ab));
                }
            }
            __syncthreads();                    // drain before row flags
            if (tid == 0) {
                __hip_atomic_fetch_add(S + (100 + (ga >> 4)) * 64, 1,
                                       __ATOMIC_RELAXED, AG);
                if (hasB)
                    __hip_atomic_fetch_add(S + (100 + (gb >> 4)) * 64, 1,
                                           __ATOMIC_RELAXED, AG);
            }
        } else {
            __syncthreads();                    // keep block-uniform sync count
        }
    }

    // ---- Phase 4: mm3 (li < 80); gate = data-dependent valid count ----
    if (li < 80) {
        const int mt3 = bat * 16 + li / 5, nt3 = li % 5;
        const int m0 = mt3 * 16;
        if (tid < 64) {
            int mv = (tid < 16) ? (mask[m0 + tid] != 0) : 0;
            unsigned long long bal = __ballot(mv);
            if (tid == 0) s_tgt = (int)__popcll(bal);
        }
        __syncthreads();
        const int tgt = s_tgt;
        if (tid == 0 && tgt > 0) spin_ge(S + (100 + mt3) * 64, tgt);
        __syncthreads();
        if (tid < 256) {
            const int w = tid >> 6, l = tid & 63;
            const int lm = l & 15, koff = (l >> 4) * 8;
            const int nrow = nt3 * 64 + w * 16 + lm;     // 0..319
            const int bval = nrow < 300;
            const int ncl = bval ? nrow : 0;
            const unsigned short* a1p = U + REPB + (m0 + lm) * 320 + koff;
            const unsigned short* a2p = U + ATB  + (m0 + lm) * 320 + koff;
            f32x4 acc = {0.f, 0.f, 0.f, 0.f};
            #pragma unroll
            for (int ks = 0; ks < 10; ++ks) {
                short8 a = *(const short8*)(a1p + ks * 32);
                short8 bB = loadB(Wf1, ncl, ks*32 + koff, isbf, bval);
                acc = __builtin_amdgcn_mfma_f32_16x16x32_bf16(a, bB, acc, 0, 0, 0);
            }
            #pragma unroll
            for (int ks = 0; ks < 10; ++ks) {
                short8 a = *(const short8*)(a2p + ks * 32);
                short8 bB = loadB(Wf2, ncl, ks*32 + koff, isbf, bval);
                acc = __builtin_amdgcn_mfma_f32_16x16x32_bf16(a, bB, acc, 0, 0, 0);
            }
            if (bval) {
                float bb = ldf(bfv, nrow, isbf);
                #pragma unroll
                for (int r = 0; r < 4; ++r) {
                    int mg = m0 + (l >> 4) * 4 + r;
                    float res = 0.f;
                    if (mask[mg]) {
                        float gp = acc[r] + bb;
                        float gate = 1.0f / (1.0f + __expf(-gp));
                        float rv = ws[ED + (mg * 300 + nrow) * 2 + 1];
                        float av = ws[ATTNF + mg * 300 + nrow];
                        res = gate * rv + (1.0f - gate) * av;
                    }
                    if (isbf) ((__hip_bfloat16*)outv)[mg * 300 + nrow] = __float2bfloat16(res);
                    else      ((float*)outv)[mg * 300 + nrow] = res;
                }
            }
        }
    }
}

extern "C" void kernel_launch(void* const* d_in, const int* in_sizes, int n_in,
                              void* d_out, int out_size, void* d_ws, size_t ws_size,
                              hipStream_t stream) {
    const void* X   = d_in[0];
    const int*  msk = (const int*)d_in[1];
    const void* Wfc = d_in[2];
    const void* bfc = d_in[3];
    const void* W1  = d_in[4];
    const void* W2  = d_in[5];
    const void* b1  = d_in[6];
    const void* Wf1 = d_in[7];
    const void* Wf2 = d_in[8];
    const void* bfv = d_in[9];
    float* ws = (float*)d_ws;

    // zero the flag state (cnt1 + cnt3 slots)
    hipMemsetAsync((char*)d_ws + (size_t)SYNC_FOFF * sizeof(float), 0, 49152, stream);

    hipLaunchKernelGGL(k_a, dim3(640), dim3(256), 0, stream,
                       X, Wfc, bfc, W1, W2, b1, ws);
    hipLaunchKernelGGL(k_b, dim3(512), dim3(320), 0, stream,
                       Wfc, Wf1, Wf2, bfv, msk, ws, d_out);
}

// Round 19
// 111.796 us; speedup vs baseline: 1.0604x; 1.0604x over previous
//
#include <hip/hip_runtime.h>
#include <hip/hip_bf16.h>

#define Dx 300

// float-offsets into ws. All inter-block intermediates written with sc0/sc1
// write-through (coherence point); consumers first-touch after their flag.
#define ED     0             // float2 [1024][300] {exd, rep}
#define HEADF  614400        // f32 [1024][300]
#define U_BASE 1228800       // ushort region (float offset)
#define REPB   0             // bf16 [1024][320]
#define ATB    327680        // bf16 [1024][320]
#define SYNC_FOFF 2000000    // flag state (memset before launch)

#define AG __HIP_MEMORY_SCOPE_AGENT

typedef __attribute__((ext_vector_type(8))) short short8;
typedef __attribute__((ext_vector_type(4))) float f32x4;

union S8 { unsigned int u[4]; unsigned short s[8]; short8 v; };

__device__ __forceinline__ float bf2f(unsigned short u) {
    union { unsigned int i; float f; } v; v.i = ((unsigned int)u) << 16; return v.f;
}
__device__ __forceinline__ unsigned short f2bf(float x) {   // round-half-up
    union { float f; unsigned int i; } u; u.f = x;
    return (unsigned short)((u.i + 0x8000u) >> 16);
}
__device__ __forceinline__ float ldf(const void* p, int idx, int isbf) {
    return isbf ? bf2f(((const unsigned short*)p)[idx]) : ((const float*)p)[idx];
}

// write-through stores (visible at coherence point once vmcnt acks)
__device__ __forceinline__ void st_wt_f32(float* p, float v) {
    asm volatile("global_store_dword %0, %1, off sc0 sc1"
                 :: "v"(p), "v"(v) : "memory");
}
__device__ __forceinline__ void st_wt_u16(unsigned short* p, unsigned short v) {
    unsigned int vv = v;
    asm volatile("global_store_short %0, %1, off sc0 sc1"
                 :: "v"(p), "v"(vv) : "memory");
}

__device__ __forceinline__ void load8f(const float* rowp, int kb, int kmax,
                                       int valid, float* x) {
    if (valid && kb + 8 <= kmax) {
        float4 a = *(const float4*)(rowp + kb);
        float4 b = *(const float4*)(rowp + kb + 4);
        x[0]=a.x; x[1]=a.y; x[2]=a.z; x[3]=a.w;
        x[4]=b.x; x[5]=b.y; x[6]=b.z; x[7]=b.w;
    } else {
        #pragma unroll
        for (int j = 0; j < 8; ++j) {
            int k = kb + j;
            x[j] = (valid && k < kmax) ? rowp[k] : 0.f;
        }
    }
}
__device__ __forceinline__ short8 pack8(const float* x) {
    S8 H;
    #pragma unroll
    for (int p = 0; p < 4; ++p) {
        union { float f; unsigned int i; } a, b;
        a.f = x[2*p]; b.f = x[2*p+1];
        H.u[p] = ((a.i + 0x8000u) >> 16) | ((b.i + 0x8000u) & 0xFFFF0000u);
    }
    return H.v;
}
__device__ __forceinline__ short8 load8bf(const unsigned short* rowp, int kb,
                                          int kmax, int valid) {
    S8 R;
    if (valid && kb + 8 <= kmax) {
        ushort4 a = *(const ushort4*)(rowp + kb);
        ushort4 b = *(const ushort4*)(rowp + kb + 4);
        R.s[0]=a.x; R.s[1]=a.y; R.s[2]=a.z; R.s[3]=a.w;
        R.s[4]=b.x; R.s[5]=b.y; R.s[6]=b.z; R.s[7]=b.w;
    } else {
        #pragma unroll
        for (int j = 0; j < 8; ++j) {
            int k = kb + j;
            R.s[j] = (valid && k < kmax) ? rowp[k] : (unsigned short)0;
        }
    }
    return R.v;
}
__device__ __forceinline__ short8 loadB(const void* W, int row, int kb, int isbf,
                                        int valid) {
    if (isbf) return load8bf((const unsigned short*)W + row * 300, kb, 300, valid);
    float t[8];
    load8f((const float*)W + row * 300, kb, 300, valid, t);
    return pack8(t);
}

__device__ __forceinline__ int xcd_id() {
    int x;
    asm volatile("s_getreg_b32 %0, hwreg(HW_REG_XCC_ID)" : "=s"(x));
    return x & 7;
}
// relaxed spin until *p >= target; bounded (lost block => visible fail)
__device__ __forceinline__ void spin_ge(int* p, int target) {
    int t = 0;
    while (__hip_atomic_load(p, __ATOMIC_RELAXED, AG) < target) {
        __builtin_amdgcn_s_sleep(1);
        if (++t > 500000) break;
    }
    asm volatile("" ::: "memory");
}

// SYNC slots (int index, 256 B apart):
//   cnt1[mt]  = mt*64           mm1 tiles (target 5)
//   cnt2[b]   = (64+b)*64       mm2 units per batch (target 160)
//   fb[b][x]  = (68+b*8+x)*64   per-XCD fan-out flags
//   cnt3[gt]  = (100+gt)*64     attn rows done per global 16-row tile

// ---------------------------------------------------------------------------
// Fused DiSA, flag-chained, XCD-PAIR batch swizzle (round-12 champion).
// THIS ROUND (micro): mm3 blend reads rv/av from REPB/ATB bf16 — lines the
// MFMA already pulled (L1/L2 hits) — instead of scattered f32 ED/ATTNF reads
// at coherence-point latency; attn drops the ATTNF f32 stores entirely.
// grid 640 x 320 (3 blocks/CU => co-resident).
// ---------------------------------------------------------------------------
__global__ __launch_bounds__(320, 4) void k_fused(
        const void* __restrict__ Xv, const int* __restrict__ mask,
        const void* __restrict__ Wfc, const void* __restrict__ bfc,
        const void* __restrict__ W1,  const void* __restrict__ W2,
        const void* __restrict__ b1v, const void* __restrict__ Wf1,
        const void* __restrict__ Wf2, const void* __restrict__ bfv,
        float* __restrict__ ws, void* __restrict__ outv) {
    __shared__ int s_isbf;
    __shared__ unsigned short vlist[256];
    __shared__ int s_cnt, s_tgt;

    const int tid = threadIdx.x;
    const int blk = blockIdx.x;
    // wave-parallel bf16 detect (1 load latency)
    if (tid < 64) {
        float v = bf2f(((const unsigned short*)Wfc)[tid]);
        int ok = fabsf(v) < 1.0f;
        unsigned long long bal = __ballot(ok);
        if (tid == 0) s_isbf = (bal == ~0ull) ? 1 : 0;
    }
    __syncthreads();
    const int isbf = s_isbf;
    unsigned short* U = (unsigned short*)(ws + U_BASE);
    int* S = (int*)(ws + SYNC_FOFF);
    const int xid = xcd_id();

    // swizzle: batch <-> XCD pair
    const int res = blk & 7;
    const int bat = res >> 1;            // 0..3
    const int li  = ((blk >> 3) << 1) | (res & 1);   // 0..159 within batch
    const int base = bat * 256;

    // ---- Phase 1: mm1  rep = elu(X@Wfc^T + bfc)  (li < 80) ----
    if (li < 80 && tid < 256) {
        const int mt_l = li / 5, nt = li % 5;
        const int mt = bat * 16 + mt_l;
        const int w = tid >> 6, l = tid & 63;
        const int m0 = mt * 16, lm = l & 15, koff = (l >> 4) * 8;
        const int nrow = nt * 64 + w * 16 + lm;          // 0..319
        const int bval = nrow < 300;
        const int ncl = bval ? nrow : 0;
        f32x4 acc = {0.f, 0.f, 0.f, 0.f};
        if (isbf) {
            const unsigned short* Xp = (const unsigned short*)Xv + (m0 + lm) * 300;
            #pragma unroll
            for (int ks = 0; ks < 10; ++ks) {
                short8 a = load8bf(Xp, ks*32 + koff, 300, 1);
                short8 b = loadB(Wfc, ncl, ks*32 + koff, 1, bval);
                acc = __builtin_amdgcn_mfma_f32_16x16x32_bf16(a, b, acc, 0, 0, 0);
            }
        } else {
            const float* Xp = (const float*)Xv + (m0 + lm) * 300;
            #pragma unroll
            for (int ks = 0; ks < 10; ++ks) {
                float t[8]; load8f(Xp, ks*32 + koff, 300, 1, t);
                short8 a = pack8(t);
                short8 b = loadB(Wfc, ncl, ks*32 + koff, 0, bval);
                acc = __builtin_amdgcn_mfma_f32_16x16x32_bf16(a, b, acc, 0, 0, 0);
            }
        }
        if (bval) {
            float bb = ldf(bfc, nrow, isbf);
            #pragma unroll
            for (int r = 0; r < 4; ++r) {
                int mg = m0 + (l >> 4) * 4 + r;
                float v = acc[r] + bb;
                v = v > 0.f ? v : (__expf(v) - 1.f);
                st_wt_f32(ws + ED + (mg * 300 + nrow) * 2 + 1, v);  // ed.y = rep
                st_wt_u16(U + REPB + mg * 320 + nrow, f2bf(v));
            }
        } else {
            #pragma unroll
            for (int r = 0; r < 4; ++r) {
                int mg = m0 + (l >> 4) * 4 + r;
                st_wt_u16(U + REPB + mg * 320 + nrow, 0);
            }
        }
    }
    __syncthreads();                                // drains all waves' vmcnt
    if (li < 80 && tid == 0)
        __hip_atomic_fetch_add(S + (bat * 16 + li / 5) * 64, 1,
                               __ATOMIC_RELAXED, AG);

    // ---- Phase 2: mm2  dep/head = rep @ {W1,W2}^T; one unit per block ----
    {
        const int mt_l = li / 10, nt10 = li % 10;
        const int mt = bat * 16 + mt_l;
        if (tid == 0) spin_ge(S + mt * 64, 5);
        __syncthreads();
        if (tid < 256) {
            const int w = tid >> 6, l = tid & 63;
            const int m0 = mt * 16, lm = l & 15, koff = (l >> 4) * 8;
            const int ng = nt10 * 64 + w * 16 + lm;      // 0..639
            const int wsel = ng < 320;
            const int wrow = wsel ? ng : ng - 320;
            const int bval = wrow < 300;
            const int ncl = bval ? wrow : 0;
            const void* Wsel = wsel ? W1 : W2;
            const unsigned short* ap = U + REPB + (m0 + lm) * 320 + koff;
            f32x4 acc = {0.f, 0.f, 0.f, 0.f};
            #pragma unroll
            for (int ks = 0; ks < 10; ++ks) {
                short8 a = *(const short8*)(ap + ks * 32);
                short8 b = loadB(Wsel, ncl, ks*32 + koff, isbf, bval);
                acc = __builtin_amdgcn_mfma_f32_16x16x32_bf16(a, b, acc, 0, 0, 0);
            }
            if (ng < 300) {
                float bb = ldf(b1v, ng, isbf);
                #pragma unroll
                for (int r = 0; r < 4; ++r) {
                    int mg = m0 + (l >> 4) * 4 + r;
                    st_wt_f32(ws + ED + (mg * 300 + ng) * 2,
                              __expf(0.4f * (acc[r] + bb)));   // ed.x
                }
            } else if (ng >= 320 && ng < 620) {
                #pragma unroll
                for (int r = 0; r < 4; ++r) {
                    int mg = m0 + (l >> 4) * 4 + r;
                    st_wt_f32(ws + HEADF + mg * 300 + (ng - 320), acc[r]);
                }
            }
        }
        __syncthreads();                        // drain before flag
        if (tid == 0) {
            int old = __hip_atomic_fetch_add(S + (64 + bat) * 64, 1,
                                             __ATOMIC_RELAXED, AG);
            if (old == 159) {                   // last mm2 unit of batch
                #pragma unroll
                for (int x = 0; x < 8; ++x)
                    __hip_atomic_store(S + (68 + bat * 8 + x) * 64, 1,
                                       __ATOMIC_RELAXED, AG);
            }
        }
    }

    // ---- Phase 3: attn; compacted valid rows, pair (2*li, 2*li+1).
    //      For row vlist[k], valid-j start is index k+1 (vlist sorted). ----
    {
        if (tid < 64) {
            int basec = 0;
            #pragma unroll
            for (int c = 0; c < 4; ++c) {
                const int j = c * 64 + tid;
                const int mv = mask[base + j] != 0;
                unsigned long long bal = __ballot(mv);
                int pos = basec + __popcll(bal & ((1ull << tid) - 1ull));
                if (mv) vlist[pos] = (unsigned short)j;
                basec += __popcll(bal);
            }
            if (tid == 0) s_cnt = basec;
        }
        if (tid == 0) spin_ge(S + (68 + bat * 8 + xid) * 64, 1);
        __syncthreads();
        const int cnt = s_cnt;
        const int iu = 2 * li;
        if (iu < cnt) {
            const int ia = vlist[iu];                    // valid row A
            const int hasB = (iu + 1 < cnt);
            const int ib = hasB ? vlist[iu + 1] : ia;    // valid row B
            const int ga = base + ia, gb = base + ib;
            const int d = tid;
            if (d >= 300) {
                st_wt_u16(U + ATB + ga * 320 + d, 0);
                if (hasB) st_wt_u16(U + ATB + gb * 320 + d, 0);
            } else {
                const float pwa = __expf(0.4f * ws[HEADF + ga * 300 + d]);
                const float pwb = __expf(0.4f * ws[HEADF + gb * 300 + d]);
                const float2* ep2 = ((const float2*)(ws + ED)) + base * Dx + d;
                float sa = 0.f, ra = 0.f, sb = 0.f, rb = 0.f;
                if (hasB) {                              // prologue: j=ib, row A only
                    float2 v = ep2[ib * Dx];
                    float ua = fmaf(v.x, pwa, 1.0f);
                    float ea = __expf(-10.0f * __builtin_amdgcn_rcpf(ua));
                    sa += ea; ra = fmaf(ea, v.y, ra);
                }
                #pragma unroll 8
                for (int t = iu + 2; t < cnt; ++t) {
                    const int j = vlist[t];
                    float2 v = ep2[j * Dx];
                    float ua = fmaf(v.x, pwa, 1.0f);
                    float ub = fmaf(v.x, pwb, 1.0f);
                    float ea = __expf(-10.0f * __builtin_amdgcn_rcpf(ua));
                    float eb = __expf(-10.0f * __builtin_amdgcn_rcpf(ub));
                    sa += ea; ra = fmaf(ea, v.y, ra);
                    sb += eb; rb = fmaf(eb, v.y, rb);
                }
                const float dena = sa + (sa == 0.f ? 1.f : 0.f) + 1e-20f;
                const float aa = ra / dena;
                st_wt_u16(U + ATB + ga * 320 + d, f2bf(aa));
                if (hasB) {
                    const float denb = sb + (sb == 0.f ? 1.f : 0.f) + 1e-20f;
                    const float ab = rb / denb;
                    st_wt_u16(U + ATB + gb * 320 + d, f2bf(ab));
                }
            }
            __syncthreads();                    // drain before row flags
            if (tid == 0) {
                __hip_atomic_fetch_add(S + (100 + (ga >> 4)) * 64, 1,
                                       __ATOMIC_RELAXED, AG);
                if (hasB)
                    __hip_atomic_fetch_add(S + (100 + (gb >> 4)) * 64, 1,
                                           __ATOMIC_RELAXED, AG);
            }
        }
    }

    // ---- Phase 4: mm3 (li < 80); gate = data-dependent valid count.
    //      Blend reads rv/av from REPB/ATB bf16 (lines already pulled by
    //      the MFMA loads => L1/L2 hits, no scattered f32 L3 reads). ----
    if (li < 80) {
        const int mt3 = bat * 16 + li / 5, nt3 = li % 5;
        const int m0 = mt3 * 16;
        if (tid < 64) {
            int mv = (tid < 16) ? (mask[m0 + tid] != 0) : 0;
            unsigned long long bal = __ballot(mv);
            if (tid == 0) s_tgt = (int)__popcll(bal);
        }
        __syncthreads();
        const int tgt = s_tgt;
        if (tid == 0 && tgt > 0) spin_ge(S + (100 + mt3) * 64, tgt);
        __syncthreads();
        if (tid < 256) {
            const int w = tid >> 6, l = tid & 63;
            const int lm = l & 15, koff = (l >> 4) * 8;
            const int nrow = nt3 * 64 + w * 16 + lm;     // 0..319
            const int bval = nrow < 300;
            const int ncl = bval ? nrow : 0;
            const unsigned short* a1p = U + REPB + (m0 + lm) * 320 + koff;
            const unsigned short* a2p = U + ATB  + (m0 + lm) * 320 + koff;
            f32x4 acc = {0.f, 0.f, 0.f, 0.f};
            #pragma unroll
            for (int ks = 0; ks < 10; ++ks) {
                short8 a = *(const short8*)(a1p + ks * 32);
                short8 bB = loadB(Wf1, ncl, ks*32 + koff, isbf, bval);
                acc = __builtin_amdgcn_mfma_f32_16x16x32_bf16(a, bB, acc, 0, 0, 0);
            }
            #pragma unroll
            for (int ks = 0; ks < 10; ++ks) {
                short8 a = *(const short8*)(a2p + ks * 32);
                short8 bB = loadB(Wf2, ncl, ks*32 + koff, isbf, bval);
                acc = __builtin_amdgcn_mfma_f32_16x16x32_bf16(a, bB, acc, 0, 0, 0);
            }
            if (bval) {
                float bb = ldf(bfv, nrow, isbf);
                #pragma unroll
                for (int r = 0; r < 4; ++r) {
                    int mg = m0 + (l >> 4) * 4 + r;
                    float res2 = 0.f;
                    if (mask[mg]) {
                        float gp = acc[r] + bb;
                        float gate = 1.0f / (1.0f + __expf(-gp));
                        float rv = bf2f(U[REPB + mg * 320 + nrow]);
                        float av = bf2f(U[ATB  + mg * 320 + nrow]);
                        res2 = gate * rv + (1.0f - gate) * av;
                    }
                    if (isbf) ((__hip_bfloat16*)outv)[mg * 300 + nrow] = __float2bfloat16(res2);
                    else      ((float*)outv)[mg * 300 + nrow] = res2;
                }
            }
        }
    }
}

extern "C" void kernel_launch(void* const* d_in, const int* in_sizes, int n_in,
                              void* d_out, int out_size, void* d_ws, size_t ws_size,
                              hipStream_t stream) {
    const void* X   = d_in[0];
    const int*  msk = (const int*)d_in[1];
    const void* Wfc = d_in[2];
    const void* bfc = d_in[3];
    const void* W1  = d_in[4];
    const void* W2  = d_in[5];
    const void* b1  = d_in[6];
    const void* Wf1 = d_in[7];
    const void* Wf2 = d_in[8];
    const void* bfv = d_in[9];
    float* ws = (float*)d_ws;

    // zero the flag state (192 slots x 256 B)
    hipMemsetAsync((char*)d_ws + (size_t)SYNC_FOFF * sizeof(float), 0, 49152, stream);

    hipLaunchKernelGGL(k_fused, dim3(640), dim3(320), 0, stream,
                       X, msk, Wfc, bfc, W1, W2, b1, Wf1, Wf2, bfv, ws, d_out);
}